// Round 11
// baseline (1195.053 us; speedup 1.0000x reference)
//
#include <hip/hip_runtime.h>
#include <cstdint>

#define NITEMS   100000
#define BROWS    512
#define DDIM     64
#define S_BLOCKS 391        // phase-1 item-blocks (256 items each)
#define IPB      256
#define OUT_FEAT 512
#define OUT_LOSS (512 + 512 * 64)
#define OUT_MSIM (OUT_LOSS + 1)

// Gumbel filter: g monotone in bits; bits >= T <=> g may exceed 6.0.
#define BITS_RAW_T 4284334592u
#define G_TE       6.001f

typedef __attribute__((ext_vector_type(8)))  short  bf16x8;
typedef __attribute__((ext_vector_type(16))) float  f32x16;
typedef unsigned long long u64;
typedef uint32_t u32;

#define ROTL(x, r) __builtin_amdgcn_alignbit((x), (x), 32u - (r))

// ---------------- Threefry-2x32-20, key=(0,42). VERIFIED R4 (absmax 0.0):
// partitionable scheme, counters (hi=0, lo=e), output = bits1 ^ bits2.
// Pair version: 2 independent chains interleaved (ILP 2 on the dep chain).
__device__ __forceinline__ void threefry_pair(u32 ea, u32 eb, u32& oa, u32& ob) {
    const u32 K1 = 42u;
    const u32 K2 = 0x1BD11BDAu ^ 42u;
    u32 a0 = 0u, a1 = ea + K1;
    u32 b0 = 0u, b1 = eb + K1;
#define TFR2(r) { a0 += a1; b0 += b1; a1 = ROTL(a1, r) ^ a0; b1 = ROTL(b1, r) ^ b0; }
    TFR2(13u) TFR2(15u) TFR2(26u) TFR2(6u)
    a0 += K1; a1 += K2 + 1u;  b0 += K1; b1 += K2 + 1u;
    TFR2(17u) TFR2(29u) TFR2(16u) TFR2(24u)
    a0 += K2; a1 += 2u;       b0 += K2; b1 += 2u;
    TFR2(13u) TFR2(15u) TFR2(26u) TFR2(6u)
    a1 += K1 + 3u;            b1 += K1 + 3u;
    TFR2(17u) TFR2(29u) TFR2(16u) TFR2(24u)
    a0 += K1; a1 += K2 + 4u;  b0 += K1; b1 += K2 + 4u;
    TFR2(13u) TFR2(15u) TFR2(26u) TFR2(6u)
    a0 += K2; a1 += 5u;       b0 += K2; b1 += 5u;
#undef TFR2
    oa = a0 ^ a1; ob = b0 ^ b1;
}

__device__ __forceinline__ float gumbel_from_bits(u32 b) {   // precise logf REQUIRED
    float f = __uint_as_float((b >> 9) | 0x3F800000u) - 1.0f;
    f = fmaxf(f, 1.17549435e-38f);
    return -logf(-logf(f));
}
__device__ __forceinline__ u32 order_map(float v) {
    u32 x = __float_as_uint(v);
    return (x & 0x80000000u) ? ~x : (x | 0x80000000u);
}
__device__ __forceinline__ float unpack_val(u64 p) {
    u32 x = (u32)(p >> 32);
    u32 f = (x & 0x80000000u) ? (x & 0x7FFFFFFFu) : ~x;
    return __uint_as_float(f);
}
__device__ __forceinline__ short f32_to_bf16_rne(float f) {
    u32 b = __float_as_uint(f);
    u32 r = (b + 0x7FFFu + ((b >> 16) & 1u)) >> 16;
    return (short)r;
}
__device__ __forceinline__ float bf16_to_f32(short h) {
    return __uint_as_float(((u32)(uint16_t)h) << 16);
}

// ---------------- K1: prep = uif GEMM (W^T in LDS) + norms + zero scalars --
__global__ void prep_kernel(const float* __restrict__ UF, const float* __restrict__ W,
                            const float* __restrict__ bias, const float* __restrict__ A,
                            float* __restrict__ uif, float* __restrict__ unorm,
                            float* __restrict__ wsAM4, float* __restrict__ out) {
    const int t = threadIdx.x, b = blockIdx.x;
    if (b == 0 && t == 0) { out[OUT_LOSS] = 0.f; out[OUT_MSIM] = 0.f; }
    if (b < 128) {
        __shared__ float Wt[128 * 65];
        for (int i = t; i < 8192; i += 256) {
            int d = i >> 7, k = i & 127;
            Wt[k * 65 + d] = W[i];
        }
        __syncthreads();
        const int row = b * 4 + (t >> 6);
        const int d   = t & 63;
        const float* u = UF + row * 128;
        float s = 0.f;
#pragma unroll 4
        for (int k = 0; k < 128; k++) s = fmaf(u[k], Wt[k * 65 + d], s);
        s += bias[d];
        uif[row * 64 + d] = s;
        float q = s * s;
#pragma unroll
        for (int o = 32; o >= 1; o >>= 1) q += __shfl_xor(q, o);
        if (d == 0) unorm[row] = sqrtf(q);
    } else {
        const int item = (b - 128) * 256 + t;
        float q = 0.f;
        if (item < NITEMS) {
            const float4* r = (const float4*)(A + (size_t)item * DDIM);
#pragma unroll
            for (int k = 0; k < 16; k++) {
                float4 x = r[k];
                q = fmaf(x.x, x.x, q); q = fmaf(x.y, x.y, q);
                q = fmaf(x.z, x.z, q); q = fmaf(x.w, x.w, q);
            }
        }
        float n = sqrtf(q);
#pragma unroll
        for (int o = 32; o >= 1; o >>= 1) n = fmaxf(n, __shfl_xor(n, o));
        if ((t & 63) == 0) wsAM4[(b - 128) * 4 + (t >> 6)] = n;
    }
}

// ---------------- K2: phase-1 MFMA score + filtered gumbel + top-2 ---------
// Two 4-tile LDS groups (32 KB): 4 barriers/block instead of 16; all global
// loads issued as register-prefetch batches >=1 tile-epilogue before use.
__global__ __launch_bounds__(256, 3) void phase1_kernel(
        const float* __restrict__ A, const float* __restrict__ uif,
        u64* __restrict__ wsT1, float* __restrict__ wsB) {
    __shared__ bf16x8 sh_ah[4 * 256];    // 16 KB  [tile-in-group][frag]
    __shared__ bf16x8 sh_al[4 * 256];    // 16 KB
    const int tid  = threadIdx.x;
    const int lane = tid & 63;
    const int wv   = tid >> 6;
    const int rg   = blockIdx.y;
    const int sb   = blockIdx.x;
    const int itembase = sb * IPB;
    const int ntiles = min(8, (NITEMS - itembase + 31) >> 5);   // 8 or 5; tiles always full (100000%32==0)
    const int row   = rg * 128 + wv * 32 + (lane & 31);
    const int khalf = (lane >> 5) * 8;

    // B-operand frags (uif rows), bf16 hi/lo split — persistent
    bf16x8 uh[4], ul[4];
#pragma unroll
    for (int s = 0; s < 4; s++) {
        const float* src = uif + row * 64 + khalf + 16 * s;
        float4 v0 = *(const float4*)src;
        float4 v1 = *(const float4*)(src + 4);
        float vv[8] = {v0.x, v0.y, v0.z, v0.w, v1.x, v1.y, v1.z, v1.w};
        bf16x8 h, l2;
#pragma unroll
        for (int j = 0; j < 8; j++) {
            short hh = f32_to_bf16_rne(vv[j]);
            float r  = vv[j] - bf16_to_f32(hh);
            h[j] = hh; l2[j] = f32_to_bf16_rne(r);
        }
        uh[s] = h; ul[s] = l2;
    }

    u64 t1p = 0ull; float t1f = -3.0e38f, t2f = -3.0e38f, sm = -3.0e38f;
    const u32 rowbase_e = (u32)row * (u32)NITEMS;

    const int s_i   = tid & 31;
    const int s_c   = tid >> 5;
    const int s_dst = (s_c >> 1) * 64 + s_i + 32 * (s_c & 1);   // R7-verified map
    const float* s_srcbase = A + (size_t)s_i * 64 + 8 * s_c;

    // prefetch group 0 (tiles 0..3, always valid since ntiles>=5)
    float4 q0[4], q1[4];
#pragma unroll
    for (int j = 0; j < 4; j++) {
        const float* src = s_srcbase + (size_t)(itembase + 32 * j) * 64;
        q0[j] = *(const float4*)(src);
        q1[j] = *(const float4*)(src + 4);
    }

    for (int g = 0; g < 2; g++) {
        const int tbase = g * 4;
        __syncthreads();                         // prior group's LDS reads done
#pragma unroll
        for (int j = 0; j < 4; j++) {
            if (tbase + j < ntiles) {
                float vv[8] = {q0[j].x, q0[j].y, q0[j].z, q0[j].w,
                               q1[j].x, q1[j].y, q1[j].z, q1[j].w};
                bf16x8 h, l2;
#pragma unroll
                for (int k = 0; k < 8; k++) {
                    short hh = f32_to_bf16_rne(vv[k]);
                    float r  = vv[k] - bf16_to_f32(hh);
                    h[k] = hh; l2[k] = f32_to_bf16_rne(r);
                }
                sh_ah[j * 256 + s_dst] = h; sh_al[j * 256 + s_dst] = l2;
            }
        }
        __syncthreads();                         // group staged
        if (g == 0) {                            // prefetch group 1 (hidden by 4 epilogues)
#pragma unroll
            for (int j = 0; j < 4; j++) {
                if (4 + j < ntiles) {
                    const float* src = s_srcbase + (size_t)(itembase + 32 * (4 + j)) * 64;
                    q0[j] = *(const float4*)(src);
                    q1[j] = *(const float4*)(src + 4);
                }
            }
        }
#pragma unroll
        for (int j = 0; j < 4; j++) {
            if (tbase + j < ntiles) {
                f32x16 acc;
#pragma unroll
                for (int z = 0; z < 16; z++) acc[z] = 0.0f;
#pragma unroll
                for (int s = 0; s < 4; s++) {
                    bf16x8 ah = sh_ah[j * 256 + s * 64 + lane];
                    bf16x8 al = sh_al[j * 256 + s * 64 + lane];
                    acc = __builtin_amdgcn_mfma_f32_32x32x16_bf16(ah, uh[s], acc, 0, 0, 0);
                    acc = __builtin_amdgcn_mfma_f32_32x32x16_bf16(al, uh[s], acc, 0, 0, 0);
                    acc = __builtin_amdgcn_mfma_f32_32x32x16_bf16(ah, ul[s], acc, 0, 0, 0);
                }
                const int tb  = itembase + (tbase + j) * 32;
                const int ib4 = tb + 4 * (lane >> 5);
#pragma unroll
                for (int i = 0; i < 16; i += 2) {
                    const int il0 = (i & 3) + 8 * (i >> 2);
                    const int il1 = ((i + 1) & 3) + 8 * ((i + 1) >> 2);
                    const int item0 = ib4 + il0;
                    const int item1 = ib4 + il1;
                    u32 r0, r1;
                    threefry_pair(rowbase_e + (u32)item0, rowbase_e + (u32)item1, r0, r1);
                    float sA = acc[i], sB = acc[i + 1];
                    sm = fmaxf(sm, fmaxf(sA, sB));
                    if (r0 >= BITS_RAW_T) {               // ~0.25% of items
                        float v = sA + gumbel_from_bits(r0);
                        if (v > t1f) {
                            t2f = t1f; t1f = v;
                            t1p = ((u64)order_map(v) << 32) | (u32)(~(u32)item0);
                        } else t2f = fmaxf(t2f, v);
                    }
                    if (r1 >= BITS_RAW_T) {
                        float v = sB + gumbel_from_bits(r1);
                        if (v > t1f) {
                            t2f = t1f; t1f = v;
                            t1p = ((u64)order_map(v) << 32) | (u32)(~(u32)item1);
                        } else t2f = fmaxf(t2f, v);
                    }
                }
            }
        }
    }

    float bnd = fmaxf(t2f, sm + G_TE);
    {
        u64   op = __shfl_xor(t1p, 32);
        float of = __shfl_xor(t1f, 32);
        float ob = __shfl_xor(bnd, 32);
        if (op > t1p) { bnd = fmaxf(fmaxf(bnd, ob), t1f); t1p = op; t1f = of; }
        else          { bnd = fmaxf(fmaxf(bnd, ob), of); }
    }
    if (lane < 32) {
        wsT1[(size_t)row * S_BLOCKS + sb] = t1p;
        wsB [(size_t)row * S_BLOCKS + sb] = bnd;
    }
}

// ---------------- K3: rowresolve = merge + certify + (resolve | exact rescan)
__global__ __launch_bounds__(256) void rowresolve_kernel(
        const u64* __restrict__ wsT1, const float* __restrict__ wsB,
        const float* __restrict__ wsAM4, const float* __restrict__ unorm,
        const float* __restrict__ uif, const float* __restrict__ A,
        const int* __restrict__ need_replace, float* __restrict__ out) {
    const int row = blockIdx.x, t = threadIdx.x;     // 256 threads
    __shared__ float Us[64];
    __shared__ u64   shP[4];
    __shared__ float shF2[4], shAM[4];
    if (t < 64) Us[t] = uif[row * 64 + t];

    float am = 0.f;
    for (int i = t; i < S_BLOCKS * 4; i += 256) am = fmaxf(am, wsAM4[i]);
    u64 p1 = 0ull; float f1 = -3.0e38f, f2 = -3.0e38f;
    for (int sbk = t; sbk < S_BLOCKS; sbk += 256) {
        u64   ep = wsT1[(size_t)row * S_BLOCKS + sbk];
        float e2 = wsB [(size_t)row * S_BLOCKS + sbk];
        if (ep > p1) { f2 = fmaxf(fmaxf(f1, e2), f2); p1 = ep; f1 = unpack_val(ep); }
        else         { float v = unpack_val(ep); f2 = fmaxf(f2, fmaxf(v, e2)); }
    }
#pragma unroll
    for (int off = 1; off < 64; off <<= 1) {
        u64   op  = __shfl_xor(p1, off);
        float of1 = __shfl_xor(f1, off);
        float of2 = __shfl_xor(f2, off);
        am = fmaxf(am, __shfl_xor(am, off));
        if (op > p1) { f2 = fmaxf(fmaxf(f1, of2), f2); p1 = op; f1 = of1; }
        else         { f2 = fmaxf(f2, fmaxf(of1, of2)); }
    }
    if ((t & 63) == 0) { shP[t >> 6] = p1; shF2[t >> 6] = f2; shAM[t >> 6] = am; }
    __syncthreads();                                  // also publishes Us

    u64 P = shP[0]; float F1 = unpack_val(P), F2 = shF2[0], AM = shAM[0];
#pragma unroll
    for (int w = 1; w < 4; w++) {
        u64 op = shP[w]; float o2 = shF2[w];
        AM = fmaxf(AM, shAM[w]);
        if (op > P) { F2 = fmaxf(fmaxf(F1, o2), F2); P = op; F1 = unpack_val(op); }
        else        { F2 = fmaxf(F2, fmaxf(unpack_val(op), o2)); }
    }
    const float E = 1.5e-4f * unorm[row] * AM + 3.0e-5f;   // R6-verified margin

    if (!(F1 - F2 > 2.0f * E)) {
        // flagged (rare, deterministic): exact f32 rescan of all items in-block
        u64 pk = 0ull;
        const u32 ebase = (u32)row * (u32)NITEMS;
        for (int base = 2 * t; base < NITEMS; base += 512) {
            u32 r0, r1;
            threefry_pair(ebase + (u32)base, ebase + (u32)base + 1u, r0, r1);
            float g0 = gumbel_from_bits(r0);
            float g1 = gumbel_from_bits(r1);
            const float4* a0 = (const float4*)(A + (size_t)base * DDIM);
            const float4* a1 = (const float4*)(A + (size_t)(base + 1) * DDIM);
            float s0 = 0.f, s1 = 0.f, s2 = 0.f, s3 = 0.f;
#pragma unroll
            for (int k = 0; k < 16; k += 2) {     // R10-identical per-item fp order
                float4 x = a0[k], y = a0[k + 1];
                s0 = fmaf(x.x, Us[4*k    ], s0);
                s0 = fmaf(x.y, Us[4*k + 1], s0);
                s0 = fmaf(x.z, Us[4*k + 2], s0);
                s0 = fmaf(x.w, Us[4*k + 3], s0);
                s1 = fmaf(y.x, Us[4*k + 4], s1);
                s1 = fmaf(y.y, Us[4*k + 5], s1);
                s1 = fmaf(y.z, Us[4*k + 6], s1);
                s1 = fmaf(y.w, Us[4*k + 7], s1);
                float4 X = a1[k], Y = a1[k + 1];
                s2 = fmaf(X.x, Us[4*k    ], s2);
                s2 = fmaf(X.y, Us[4*k + 1], s2);
                s2 = fmaf(X.z, Us[4*k + 2], s2);
                s2 = fmaf(X.w, Us[4*k + 3], s2);
                s3 = fmaf(Y.x, Us[4*k + 4], s3);
                s3 = fmaf(Y.y, Us[4*k + 5], s3);
                s3 = fmaf(Y.z, Us[4*k + 6], s3);
                s3 = fmaf(Y.w, Us[4*k + 7], s3);
            }
            float v0 = (s0 + s1) + g0;
            float v1 = (s2 + s3) + g1;
            u64 c0 = ((u64)order_map(v0) << 32) | (u32)(~(u32)base);
            u64 c1 = ((u64)order_map(v1) << 32) | (u32)(~(u32)(base + 1));
            if (c0 > pk) pk = c0;
            if (c1 > pk) pk = c1;
        }
#pragma unroll
        for (int off = 1; off < 64; off <<= 1) {
            u64 o = __shfl_xor(pk, off);
            pk = (o > pk) ? o : pk;
        }
        __syncthreads();                          // reuse shP safely
        if ((t & 63) == 0) shP[t >> 6] = pk;
        __syncthreads();
        P = shP[0];
#pragma unroll
        for (int w = 1; w < 4; w++) if (shP[w] > P) P = shP[w];
    }

    // resolve (all threads agree on P)
    if (t < 64) {
        const int idx = (int)(~(u32)(P & 0xFFFFFFFFull));
        float fr = A[(size_t)idx * DDIM + t];
        out[OUT_FEAT + row * DDIM + t] = fr;
        int   item = need_replace[2 * row + 1];
        float fa   = A[(size_t)item * DDIM + t];
        float dot = fa * fr, na2 = fa * fa, nb2 = fr * fr;
#pragma unroll
        for (int o = 32; o >= 1; o >>= 1) {
            dot += __shfl_down(dot, o);
            na2 += __shfl_down(na2, o);
            nb2 += __shfl_down(nb2, o);
        }
        if (t == 0) {
            out[row] = (float)idx;
            float denom = fmaxf(sqrtf(na2) * sqrtf(nb2), 1e-6f);
            float sim = (dot / denom + 1.0f) * 0.5f;
            float d = sim - 0.5f;
            atomicAdd(&out[OUT_LOSS], d * d * (1.0f / 512.0f));
            atomicAdd(&out[OUT_MSIM], sim * (1.0f / 512.0f));
        }
    }
}

extern "C" void kernel_launch(void* const* d_in, const int* in_sizes, int n_in,
                              void* d_out, int out_size, void* d_ws, size_t ws_size,
                              hipStream_t stream) {
    (void)in_sizes; (void)n_in; (void)out_size; (void)ws_size;
    const int*   need_replace = (const int*)d_in[0];
    const float* UF           = (const float*)d_in[1];
    const float* A            = (const float*)d_in[2];
    const float* W            = (const float*)d_in[3];
    const float* bias         = (const float*)d_in[4];
    float* out = (float*)d_out;

    char* ws = (char*)d_ws;                              // ~2.54 MB total
    u64*   wsT1    = (u64*)  (ws);                       // 512*391*8 = 1601536
    float* wsB     = (float*)(ws + 1601536);             // 800768
    float* uif     = (float*)(ws + 2402304);             // 131072
    float* unorm   = (float*)(ws + 2533376);             // 2048
    float* wsAM4   = (float*)(ws + 2535424);             // 6256

    prep_kernel<<<519, 256, 0, stream>>>(UF, W, bias, A, uif, unorm, wsAM4, out);
    phase1_kernel<<<dim3(S_BLOCKS, 4), 256, 0, stream>>>(A, uif, wsT1, wsB);
    rowresolve_kernel<<<BROWS, 256, 0, stream>>>(wsT1, wsB, wsAM4, unorm, uif, A,
                                                 need_replace, out);
}

// Round 12
// 271.825 us; speedup vs baseline: 4.3964x; 4.3964x over previous
//
#include <hip/hip_runtime.h>
#include <cstdint>

#define NITEMS   100000
#define BROWS    512
#define DDIM     64
#define S_BLOCKS 391        // phase-1 item-blocks (256 items each)
#define IPB      256
#define OUT_FEAT 512
#define OUT_LOSS (512 + 512 * 64)
#define OUT_MSIM (OUT_LOSS + 1)

// Gumbel filter: g monotone in bits; bits >= T <=> g may exceed 6.0.
#define BITS_RAW_T 4284334592u
#define G_TE       6.001f

typedef __attribute__((ext_vector_type(8)))  short  bf16x8;
typedef __attribute__((ext_vector_type(16))) float  f32x16;
typedef unsigned long long u64;
typedef uint32_t u32;

#define ROTL(x, r) __builtin_amdgcn_alignbit((x), (x), 32u - (r))

// ---------------- Threefry-2x32-20, key=(0,42). VERIFIED R4 (absmax 0.0):
// partitionable scheme, counters (hi=0, lo=e), output = bits1 ^ bits2.
__device__ __forceinline__ u32 threefry_0_42_xor(u32 e) {
    const u32 K1 = 42u;
    const u32 K2 = 0x1BD11BDAu ^ 42u;   // K0 = 0
    u32 x0 = 0u;
    u32 x1 = e + K1;
#define TFR(r) { x0 += x1; x1 = ROTL(x1, r) ^ x0; }
    TFR(13u) TFR(15u) TFR(26u) TFR(6u)
    x0 += K1;  x1 += K2 + 1u;
    TFR(17u) TFR(29u) TFR(16u) TFR(24u)
    x0 += K2;  x1 += 2u;
    TFR(13u) TFR(15u) TFR(26u) TFR(6u)
    x1 += K1 + 3u;
    TFR(17u) TFR(29u) TFR(16u) TFR(24u)
    x0 += K1;  x1 += K2 + 4u;
    TFR(13u) TFR(15u) TFR(26u) TFR(6u)
    x0 += K2;  x1 += 5u;
#undef TFR
    return x0 ^ x1;
}

// Pair version: 2 independent chains interleaved (ILP 2 on the dep chain).
__device__ __forceinline__ void threefry_pair(u32 ea, u32 eb, u32& oa, u32& ob) {
    const u32 K1 = 42u;
    const u32 K2 = 0x1BD11BDAu ^ 42u;
    u32 a0 = 0u, a1 = ea + K1;
    u32 b0 = 0u, b1 = eb + K1;
#define TFR2(r) { a0 += a1; b0 += b1; a1 = ROTL(a1, r) ^ a0; b1 = ROTL(b1, r) ^ b0; }
    TFR2(13u) TFR2(15u) TFR2(26u) TFR2(6u)
    a0 += K1; a1 += K2 + 1u;  b0 += K1; b1 += K2 + 1u;
    TFR2(17u) TFR2(29u) TFR2(16u) TFR2(24u)
    a0 += K2; a1 += 2u;       b0 += K2; b1 += 2u;
    TFR2(13u) TFR2(15u) TFR2(26u) TFR2(6u)
    a1 += K1 + 3u;            b1 += K1 + 3u;
    TFR2(17u) TFR2(29u) TFR2(16u) TFR2(24u)
    a0 += K1; a1 += K2 + 4u;  b0 += K1; b1 += K2 + 4u;
    TFR2(13u) TFR2(15u) TFR2(26u) TFR2(6u)
    a0 += K2; a1 += 5u;       b0 += K2; b1 += 5u;
#undef TFR2
    oa = a0 ^ a1; ob = b0 ^ b1;
}

__device__ __forceinline__ float gumbel_from_bits(u32 b) {   // precise logf REQUIRED
    float f = __uint_as_float((b >> 9) | 0x3F800000u) - 1.0f;
    f = fmaxf(f, 1.17549435e-38f);
    return -logf(-logf(f));
}
__device__ __forceinline__ u32 order_map(float v) {
    u32 x = __float_as_uint(v);
    return (x & 0x80000000u) ? ~x : (x | 0x80000000u);
}
__device__ __forceinline__ float unpack_val(u64 p) {
    u32 x = (u32)(p >> 32);
    u32 f = (x & 0x80000000u) ? (x & 0x7FFFFFFFu) : ~x;
    return __uint_as_float(f);
}
__device__ __forceinline__ short f32_to_bf16_rne(float f) {
    u32 b = __float_as_uint(f);
    u32 r = (b + 0x7FFFu + ((b >> 16) & 1u)) >> 16;
    return (short)r;
}
__device__ __forceinline__ float bf16_to_f32(short h) {
    return __uint_as_float(((u32)(uint16_t)h) << 16);
}

// ---------------- K1: prep = uif GEMM (W^T in LDS) + norms + Amax ----------
__global__ void prep_kernel(const float* __restrict__ UF, const float* __restrict__ W,
                            const float* __restrict__ bias, const float* __restrict__ A,
                            float* __restrict__ uif, float* __restrict__ unorm,
                            u32* __restrict__ amax_bits, float* __restrict__ out) {
    const int t = threadIdx.x, b = blockIdx.x;
    if (b == 0 && t == 0) { out[OUT_LOSS] = 0.f; out[OUT_MSIM] = 0.f; }
    if (b < 128) {
        __shared__ float Wt[128 * 65];
        for (int i = t; i < 8192; i += 256) {
            int d = i >> 7, k = i & 127;
            Wt[k * 65 + d] = W[i];
        }
        __syncthreads();
        const int row = b * 4 + (t >> 6);
        const int d   = t & 63;
        const float* u = UF + row * 128;
        float s = 0.f;
#pragma unroll 4
        for (int k = 0; k < 128; k++) s = fmaf(u[k], Wt[k * 65 + d], s);
        s += bias[d];
        uif[row * 64 + d] = s;
        float q = s * s;
#pragma unroll
        for (int o = 32; o >= 1; o >>= 1) q += __shfl_xor(q, o);
        if (d == 0) unorm[row] = sqrtf(q);
    } else {
        const int item = (b - 128) * 256 + t;
        float q = 0.f;
        if (item < NITEMS) {
            const float4* r = (const float4*)(A + (size_t)item * DDIM);
#pragma unroll
            for (int k = 0; k < 16; k++) {
                float4 x = r[k];
                q = fmaf(x.x, x.x, q); q = fmaf(x.y, x.y, q);
                q = fmaf(x.z, x.z, q); q = fmaf(x.w, x.w, q);
            }
        }
        float n = sqrtf(q);
#pragma unroll
        for (int o = 32; o >= 1; o >>= 1) n = fmaxf(n, __shfl_xor(n, o));
        // amax_bits memset to 0 on-stream before this kernel; norms >= 0 so
        // u32 compare == float compare.
        if ((t & 63) == 0) atomicMax(amax_bits, __float_as_uint(n));
    }
}

// ---------------- K2: phase-1 MFMA score + filtered gumbel + top-2 ---------
// Two 4-tile LDS groups (32 KB): 4 barriers/block; register-prefetched loads.
__global__ __launch_bounds__(256, 3) void phase1_kernel(
        const float* __restrict__ A, const float* __restrict__ uif,
        u64* __restrict__ wsT1, float* __restrict__ wsB) {
    __shared__ bf16x8 sh_ah[4 * 256];    // 16 KB
    __shared__ bf16x8 sh_al[4 * 256];    // 16 KB
    const int tid  = threadIdx.x;
    const int lane = tid & 63;
    const int wv   = tid >> 6;
    const int rg   = blockIdx.y;
    const int sb   = blockIdx.x;
    const int itembase = sb * IPB;
    const int ntiles = min(8, (NITEMS - itembase + 31) >> 5);   // 8 or 5; tiles always full
    const int row   = rg * 128 + wv * 32 + (lane & 31);
    const int khalf = (lane >> 5) * 8;

    bf16x8 uh[4], ul[4];
#pragma unroll
    for (int s = 0; s < 4; s++) {
        const float* src = uif + row * 64 + khalf + 16 * s;
        float4 v0 = *(const float4*)src;
        float4 v1 = *(const float4*)(src + 4);
        float vv[8] = {v0.x, v0.y, v0.z, v0.w, v1.x, v1.y, v1.z, v1.w};
        bf16x8 h, l2;
#pragma unroll
        for (int j = 0; j < 8; j++) {
            short hh = f32_to_bf16_rne(vv[j]);
            float r  = vv[j] - bf16_to_f32(hh);
            h[j] = hh; l2[j] = f32_to_bf16_rne(r);
        }
        uh[s] = h; ul[s] = l2;
    }

    u64 t1p = 0ull; float t1f = -3.0e38f, t2f = -3.0e38f, sm = -3.0e38f;
    const u32 rowbase_e = (u32)row * (u32)NITEMS;

    const int s_i   = tid & 31;
    const int s_c   = tid >> 5;
    const int s_dst = (s_c >> 1) * 64 + s_i + 32 * (s_c & 1);   // R7-verified map
    const float* s_srcbase = A + (size_t)s_i * 64 + 8 * s_c;

    float4 q0[4], q1[4];
#pragma unroll
    for (int j = 0; j < 4; j++) {
        const float* src = s_srcbase + (size_t)(itembase + 32 * j) * 64;
        q0[j] = *(const float4*)(src);
        q1[j] = *(const float4*)(src + 4);
    }

    for (int g = 0; g < 2; g++) {
        const int tbase = g * 4;
        __syncthreads();
#pragma unroll
        for (int j = 0; j < 4; j++) {
            if (tbase + j < ntiles) {
                float vv[8] = {q0[j].x, q0[j].y, q0[j].z, q0[j].w,
                               q1[j].x, q1[j].y, q1[j].z, q1[j].w};
                bf16x8 h, l2;
#pragma unroll
                for (int k = 0; k < 8; k++) {
                    short hh = f32_to_bf16_rne(vv[k]);
                    float r  = vv[k] - bf16_to_f32(hh);
                    h[k] = hh; l2[k] = f32_to_bf16_rne(r);
                }
                sh_ah[j * 256 + s_dst] = h; sh_al[j * 256 + s_dst] = l2;
            }
        }
        __syncthreads();
        if (g == 0) {
#pragma unroll
            for (int j = 0; j < 4; j++) {
                if (4 + j < ntiles) {
                    const float* src = s_srcbase + (size_t)(itembase + 32 * (4 + j)) * 64;
                    q0[j] = *(const float4*)(src);
                    q1[j] = *(const float4*)(src + 4);
                }
            }
        }
#pragma unroll
        for (int j = 0; j < 4; j++) {
            if (tbase + j < ntiles) {
                f32x16 acc;
#pragma unroll
                for (int z = 0; z < 16; z++) acc[z] = 0.0f;
#pragma unroll
                for (int s = 0; s < 4; s++) {
                    bf16x8 ah = sh_ah[j * 256 + s * 64 + lane];
                    bf16x8 al = sh_al[j * 256 + s * 64 + lane];
                    acc = __builtin_amdgcn_mfma_f32_32x32x16_bf16(ah, uh[s], acc, 0, 0, 0);
                    acc = __builtin_amdgcn_mfma_f32_32x32x16_bf16(al, uh[s], acc, 0, 0, 0);
                    acc = __builtin_amdgcn_mfma_f32_32x32x16_bf16(ah, ul[s], acc, 0, 0, 0);
                }
                const int tb  = itembase + (tbase + j) * 32;
                const int ib4 = tb + 4 * (lane >> 5);
#pragma unroll
                for (int i = 0; i < 16; i += 2) {
                    const int il0 = (i & 3) + 8 * (i >> 2);
                    const int il1 = ((i + 1) & 3) + 8 * ((i + 1) >> 2);
                    const int item0 = ib4 + il0;
                    const int item1 = ib4 + il1;
                    u32 r0, r1;
                    threefry_pair(rowbase_e + (u32)item0, rowbase_e + (u32)item1, r0, r1);
                    float sA = acc[i], sB = acc[i + 1];
                    sm = fmaxf(sm, fmaxf(sA, sB));
                    if (r0 >= BITS_RAW_T) {               // ~0.25% of items
                        float v = sA + gumbel_from_bits(r0);
                        if (v > t1f) {
                            t2f = t1f; t1f = v;
                            t1p = ((u64)order_map(v) << 32) | (u32)(~(u32)item0);
                        } else t2f = fmaxf(t2f, v);
                    }
                    if (r1 >= BITS_RAW_T) {
                        float v = sB + gumbel_from_bits(r1);
                        if (v > t1f) {
                            t2f = t1f; t1f = v;
                            t1p = ((u64)order_map(v) << 32) | (u32)(~(u32)item1);
                        } else t2f = fmaxf(t2f, v);
                    }
                }
            }
        }
    }

    float bnd = fmaxf(t2f, sm + G_TE);
    {
        u64   op = __shfl_xor(t1p, 32);
        float of = __shfl_xor(t1f, 32);
        float ob = __shfl_xor(bnd, 32);
        if (op > t1p) { bnd = fmaxf(fmaxf(bnd, ob), t1f); t1p = op; t1f = of; }
        else          { bnd = fmaxf(fmaxf(bnd, ob), of); }
    }
    if (lane < 32) {
        wsT1[(size_t)row * S_BLOCKS + sb] = t1p;
        wsB [(size_t)row * S_BLOCKS + sb] = bnd;
    }
}

// ---------------- K3: rowresolve = merge + certify + candidate rescan ------
// Flagged rows (gap <= 2E, ~1/run): rescan ONLY sb-blocks whose
// max(top1_sb, bound_sb) >= F1 - 2E — provably the only blocks that can hold
// the argmax (item_true <= approx+E < F1-E <= true_top). Typically 1-2 sbs.
__global__ __launch_bounds__(256) void rowresolve_kernel(
        const u64* __restrict__ wsT1, const float* __restrict__ wsB,
        const u32* __restrict__ amax_bits, const float* __restrict__ unorm,
        const float* __restrict__ uif, const float* __restrict__ A,
        const int* __restrict__ need_replace, float* __restrict__ out) {
    const int row = blockIdx.x, t = threadIdx.x;     // 256 threads
    __shared__ float Us[64];
    __shared__ u64   shP[4];
    __shared__ float shF2[4];
    if (t < 64) Us[t] = uif[row * 64 + t];

    u64 p1 = 0ull; float f1 = -3.0e38f, f2 = -3.0e38f;
    for (int sbk = t; sbk < S_BLOCKS; sbk += 256) {
        u64   ep = wsT1[(size_t)row * S_BLOCKS + sbk];
        float e2 = wsB [(size_t)row * S_BLOCKS + sbk];
        if (ep > p1) { f2 = fmaxf(fmaxf(f1, e2), f2); p1 = ep; f1 = unpack_val(ep); }
        else         { float v = unpack_val(ep); f2 = fmaxf(f2, fmaxf(v, e2)); }
    }
#pragma unroll
    for (int off = 1; off < 64; off <<= 1) {
        u64   op  = __shfl_xor(p1, off);
        float of1 = __shfl_xor(f1, off);
        float of2 = __shfl_xor(f2, off);
        if (op > p1) { f2 = fmaxf(fmaxf(f1, of2), f2); p1 = op; f1 = of1; }
        else         { f2 = fmaxf(f2, fmaxf(of1, of2)); }
    }
    if ((t & 63) == 0) { shP[t >> 6] = p1; shF2[t >> 6] = f2; }
    __syncthreads();                                  // also publishes Us

    u64 P = shP[0]; float F1 = unpack_val(P), F2 = shF2[0];
#pragma unroll
    for (int w = 1; w < 4; w++) {
        u64 op = shP[w]; float o2 = shF2[w];
        if (op > P) { F2 = fmaxf(fmaxf(F1, o2), F2); P = op; F1 = unpack_val(op); }
        else        { F2 = fmaxf(F2, fmaxf(unpack_val(op), o2)); }
    }
    const float Amax = __uint_as_float(*amax_bits);
    const float E = 1.5e-4f * unorm[row] * Amax + 3.0e-5f;   // R6-verified margin

    if (!(F1 - F2 > 2.0f * E)) {
        const float thresh = F1 - 2.0f * E;
        u64 pk = 0ull;
        for (int sb = 0; sb < S_BLOCKS; sb++) {
            u64   tp = wsT1[(size_t)row * S_BLOCKS + sb];   // broadcast reads
            float bb = wsB [(size_t)row * S_BLOCKS + sb];
            if (fmaxf(unpack_val(tp), bb) >= thresh) {      // candidate sb (~1-2)
                const int item = sb * IPB + t;
                if (item < NITEMS) {
                    u32 rb  = threefry_0_42_xor((u32)row * (u32)NITEMS + (u32)item);
                    float g = gumbel_from_bits(rb);
                    const float4* a4 = (const float4*)(A + (size_t)item * DDIM);
                    float s0 = 0.f, s1 = 0.f;
#pragma unroll
                    for (int k = 0; k < 16; k += 2) {       // R5-verified op order
                        float4 x = a4[k];
                        float4 y = a4[k + 1];
                        s0 = fmaf(x.x, Us[4*k    ], s0);
                        s0 = fmaf(x.y, Us[4*k + 1], s0);
                        s0 = fmaf(x.z, Us[4*k + 2], s0);
                        s0 = fmaf(x.w, Us[4*k + 3], s0);
                        s1 = fmaf(y.x, Us[4*k + 4], s1);
                        s1 = fmaf(y.y, Us[4*k + 5], s1);
                        s1 = fmaf(y.z, Us[4*k + 6], s1);
                        s1 = fmaf(y.w, Us[4*k + 7], s1);
                    }
                    float v = (s0 + s1) + g;
                    u64 c = ((u64)order_map(v) << 32) | (u32)(~(u32)item);
                    if (c > pk) pk = c;
                }
            }
        }
#pragma unroll
        for (int off = 1; off < 64; off <<= 1) {
            u64 o = __shfl_xor(pk, off);
            pk = (o > pk) ? o : pk;
        }
        __syncthreads();                          // reuse shP safely
        if ((t & 63) == 0) shP[t >> 6] = pk;
        __syncthreads();
        P = shP[0];
#pragma unroll
        for (int w = 1; w < 4; w++) if (shP[w] > P) P = shP[w];
    }

    if (t < 64) {
        const int idx = (int)(~(u32)(P & 0xFFFFFFFFull));
        float fr = A[(size_t)idx * DDIM + t];
        out[OUT_FEAT + row * DDIM + t] = fr;
        int   item = need_replace[2 * row + 1];
        float fa   = A[(size_t)item * DDIM + t];
        float dot = fa * fr, na2 = fa * fa, nb2 = fr * fr;
#pragma unroll
        for (int o = 32; o >= 1; o >>= 1) {
            dot += __shfl_down(dot, o);
            na2 += __shfl_down(na2, o);
            nb2 += __shfl_down(nb2, o);
        }
        if (t == 0) {
            out[row] = (float)idx;
            float denom = fmaxf(sqrtf(na2) * sqrtf(nb2), 1e-6f);
            float sim = (dot / denom + 1.0f) * 0.5f;
            float d = sim - 0.5f;
            atomicAdd(&out[OUT_LOSS], d * d * (1.0f / 512.0f));
            atomicAdd(&out[OUT_MSIM], sim * (1.0f / 512.0f));
        }
    }
}

extern "C" void kernel_launch(void* const* d_in, const int* in_sizes, int n_in,
                              void* d_out, int out_size, void* d_ws, size_t ws_size,
                              hipStream_t stream) {
    (void)in_sizes; (void)n_in; (void)out_size; (void)ws_size;
    const int*   need_replace = (const int*)d_in[0];
    const float* UF           = (const float*)d_in[1];
    const float* A            = (const float*)d_in[2];
    const float* W            = (const float*)d_in[3];
    const float* bias         = (const float*)d_in[4];
    float* out = (float*)d_out;

    char* ws = (char*)d_ws;                              // ~2.54 MB total
    u64*   wsT1    = (u64*)  (ws);                       // 512*391*8 = 1601536
    float* wsB     = (float*)(ws + 1601536);             // 800768
    float* uif     = (float*)(ws + 2402304);             // 131072
    float* unorm   = (float*)(ws + 2533376);             // 2048
    u32*   amax    = (u32*)  (ws + 2535424);             // 4

    hipMemsetAsync(amax, 0, 4, stream);                  // capture-safe stream memset
    prep_kernel<<<519, 256, 0, stream>>>(UF, W, bias, A, uif, unorm, amax, out);
    phase1_kernel<<<dim3(S_BLOCKS, 4), 256, 0, stream>>>(A, uif, wsT1, wsB);
    rowresolve_kernel<<<BROWS, 256, 0, stream>>>(wsT1, wsB, amax, unorm, uif, A,
                                                 need_replace, out);
}

// Round 13
// 268.451 us; speedup vs baseline: 4.4517x; 1.0126x over previous
//
#include <hip/hip_runtime.h>
#include <cstdint>

#define NITEMS   100000
#define BROWS    512
#define DDIM     64
#define S_BLOCKS 391        // phase-1 item-blocks (256 items each)
#define IPB      256
#define OUT_FEAT 512
#define OUT_LOSS (512 + 512 * 64)
#define OUT_MSIM (OUT_LOSS + 1)

// Gumbel filter: g monotone in bits; bits >= T <=> g may exceed 6.0.
#define BITS_RAW_T 4284334592u
#define G_TE       6.001f

typedef __attribute__((ext_vector_type(8)))  short  bf16x8;
typedef __attribute__((ext_vector_type(16))) float  f32x16;
typedef unsigned long long u64;
typedef uint32_t u32;

#define ROTL(x, r) __builtin_amdgcn_alignbit((x), (x), 32u - (r))

// ---------------- Threefry-2x32-20, key=(0,42). VERIFIED R4 (absmax 0.0):
// partitionable scheme, counters (hi=0, lo=e), output = bits1 ^ bits2.
__device__ __forceinline__ u32 threefry_0_42_xor(u32 e) {
    const u32 K1 = 42u;
    const u32 K2 = 0x1BD11BDAu ^ 42u;   // K0 = 0
    u32 x0 = 0u;
    u32 x1 = e + K1;
#define TFR(r) { x0 += x1; x1 = ROTL(x1, r) ^ x0; }
    TFR(13u) TFR(15u) TFR(26u) TFR(6u)
    x0 += K1;  x1 += K2 + 1u;
    TFR(17u) TFR(29u) TFR(16u) TFR(24u)
    x0 += K2;  x1 += 2u;
    TFR(13u) TFR(15u) TFR(26u) TFR(6u)
    x1 += K1 + 3u;
    TFR(17u) TFR(29u) TFR(16u) TFR(24u)
    x0 += K1;  x1 += K2 + 4u;
    TFR(13u) TFR(15u) TFR(26u) TFR(6u)
    x0 += K2;  x1 += 5u;
#undef TFR
    return x0 ^ x1;
}

// Pair version: 2 independent chains interleaved (ILP 2 on the dep chain).
__device__ __forceinline__ void threefry_pair(u32 ea, u32 eb, u32& oa, u32& ob) {
    const u32 K1 = 42u;
    const u32 K2 = 0x1BD11BDAu ^ 42u;
    u32 a0 = 0u, a1 = ea + K1;
    u32 b0 = 0u, b1 = eb + K1;
#define TFR2(r) { a0 += a1; b0 += b1; a1 = ROTL(a1, r) ^ a0; b1 = ROTL(b1, r) ^ b0; }
    TFR2(13u) TFR2(15u) TFR2(26u) TFR2(6u)
    a0 += K1; a1 += K2 + 1u;  b0 += K1; b1 += K2 + 1u;
    TFR2(17u) TFR2(29u) TFR2(16u) TFR2(24u)
    a0 += K2; a1 += 2u;       b0 += K2; b1 += 2u;
    TFR2(13u) TFR2(15u) TFR2(26u) TFR2(6u)
    a1 += K1 + 3u;            b1 += K1 + 3u;
    TFR2(17u) TFR2(29u) TFR2(16u) TFR2(24u)
    a0 += K1; a1 += K2 + 4u;  b0 += K1; b1 += K2 + 4u;
    TFR2(13u) TFR2(15u) TFR2(26u) TFR2(6u)
    a0 += K2; a1 += 5u;       b0 += K2; b1 += 5u;
#undef TFR2
    oa = a0 ^ a1; ob = b0 ^ b1;
}

__device__ __forceinline__ float gumbel_from_bits(u32 b) {   // precise logf REQUIRED
    float f = __uint_as_float((b >> 9) | 0x3F800000u) - 1.0f;
    f = fmaxf(f, 1.17549435e-38f);
    return -logf(-logf(f));
}
__device__ __forceinline__ u32 order_map(float v) {
    u32 x = __float_as_uint(v);
    return (x & 0x80000000u) ? ~x : (x | 0x80000000u);
}
__device__ __forceinline__ float unpack_val(u64 p) {
    u32 x = (u32)(p >> 32);
    u32 f = (x & 0x80000000u) ? (x & 0x7FFFFFFFu) : ~x;
    return __uint_as_float(f);
}
__device__ __forceinline__ short f32_to_bf16_rne(float f) {
    u32 b = __float_as_uint(f);
    u32 r = (b + 0x7FFFu + ((b >> 16) & 1u)) >> 16;
    return (short)r;
}
__device__ __forceinline__ float bf16_to_f32(short h) {
    return __uint_as_float(((u32)(uint16_t)h) << 16);
}

// ---------------- K1: prep = uif GEMM (W^T in LDS) + norms (no atomics) ----
__global__ void prep_kernel(const float* __restrict__ UF, const float* __restrict__ W,
                            const float* __restrict__ bias, const float* __restrict__ A,
                            float* __restrict__ uif, float* __restrict__ unorm,
                            float* __restrict__ wsAM4, float* __restrict__ out) {
    const int t = threadIdx.x, b = blockIdx.x;
    if (b == 0 && t == 0) { out[OUT_LOSS] = 0.f; out[OUT_MSIM] = 0.f; }
    if (b < 128) {
        __shared__ float Wt[128 * 65];
        for (int i = t; i < 8192; i += 256) {
            int d = i >> 7, k = i & 127;
            Wt[k * 65 + d] = W[i];
        }
        __syncthreads();
        const int row = b * 4 + (t >> 6);
        const int d   = t & 63;
        const float* u = UF + row * 128;
        float s = 0.f;
#pragma unroll 4
        for (int k = 0; k < 128; k++) s = fmaf(u[k], Wt[k * 65 + d], s);
        s += bias[d];
        uif[row * 64 + d] = s;
        float q = s * s;
#pragma unroll
        for (int o = 32; o >= 1; o >>= 1) q += __shfl_xor(q, o);
        if (d == 0) unorm[row] = sqrtf(q);
    } else {
        const int item = (b - 128) * 256 + t;
        float q = 0.f;
        if (item < NITEMS) {
            const float4* r = (const float4*)(A + (size_t)item * DDIM);
#pragma unroll
            for (int k = 0; k < 16; k++) {
                float4 x = r[k];
                q = fmaf(x.x, x.x, q); q = fmaf(x.y, x.y, q);
                q = fmaf(x.z, x.z, q); q = fmaf(x.w, x.w, q);
            }
        }
        float n = sqrtf(q);
#pragma unroll
        for (int o = 32; o >= 1; o >>= 1) n = fmaxf(n, __shfl_xor(n, o));
        if ((t & 63) == 0) wsAM4[(b - 128) * 4 + (t >> 6)] = n;
    }
}

// ---------------- K2: phase-1 MFMA score + filtered gumbel + top-2 ---------
// (256,5): LDS 32KB permits 5 blocks/CU; VGPR 60 well under the 102 cap.
// Occupancy ceiling 37.5% -> 62.5% vs R12's (256,3).
__global__ __launch_bounds__(256, 5) void phase1_kernel(
        const float* __restrict__ A, const float* __restrict__ uif,
        u64* __restrict__ wsT1, float* __restrict__ wsB) {
    __shared__ bf16x8 sh_ah[4 * 256];    // 16 KB
    __shared__ bf16x8 sh_al[4 * 256];    // 16 KB
    const int tid  = threadIdx.x;
    const int lane = tid & 63;
    const int wv   = tid >> 6;
    const int rg   = blockIdx.y;
    const int sb   = blockIdx.x;
    const int itembase = sb * IPB;
    const int ntiles = min(8, (NITEMS - itembase + 31) >> 5);   // 8 or 5; tiles always full
    const int row   = rg * 128 + wv * 32 + (lane & 31);
    const int khalf = (lane >> 5) * 8;

    bf16x8 uh[4], ul[4];
#pragma unroll
    for (int s = 0; s < 4; s++) {
        const float* src = uif + row * 64 + khalf + 16 * s;
        float4 v0 = *(const float4*)src;
        float4 v1 = *(const float4*)(src + 4);
        float vv[8] = {v0.x, v0.y, v0.z, v0.w, v1.x, v1.y, v1.z, v1.w};
        bf16x8 h, l2;
#pragma unroll
        for (int j = 0; j < 8; j++) {
            short hh = f32_to_bf16_rne(vv[j]);
            float r  = vv[j] - bf16_to_f32(hh);
            h[j] = hh; l2[j] = f32_to_bf16_rne(r);
        }
        uh[s] = h; ul[s] = l2;
    }

    u64 t1p = 0ull; float t1f = -3.0e38f, t2f = -3.0e38f, sm = -3.0e38f;
    const u32 rowbase_e = (u32)row * (u32)NITEMS;

    const int s_i   = tid & 31;
    const int s_c   = tid >> 5;
    const int s_dst = (s_c >> 1) * 64 + s_i + 32 * (s_c & 1);   // R7-verified map
    const float* s_srcbase = A + (size_t)s_i * 64 + 8 * s_c;

    float4 q0[4], q1[4];
#pragma unroll
    for (int j = 0; j < 4; j++) {
        const float* src = s_srcbase + (size_t)(itembase + 32 * j) * 64;
        q0[j] = *(const float4*)(src);
        q1[j] = *(const float4*)(src + 4);
    }

    for (int g = 0; g < 2; g++) {
        const int tbase = g * 4;
        __syncthreads();
#pragma unroll
        for (int j = 0; j < 4; j++) {
            if (tbase + j < ntiles) {
                float vv[8] = {q0[j].x, q0[j].y, q0[j].z, q0[j].w,
                               q1[j].x, q1[j].y, q1[j].z, q1[j].w};
                bf16x8 h, l2;
#pragma unroll
                for (int k = 0; k < 8; k++) {
                    short hh = f32_to_bf16_rne(vv[k]);
                    float r  = vv[k] - bf16_to_f32(hh);
                    h[k] = hh; l2[k] = f32_to_bf16_rne(r);
                }
                sh_ah[j * 256 + s_dst] = h; sh_al[j * 256 + s_dst] = l2;
            }
        }
        __syncthreads();
        if (g == 0) {
#pragma unroll
            for (int j = 0; j < 4; j++) {
                if (4 + j < ntiles) {
                    const float* src = s_srcbase + (size_t)(itembase + 32 * (4 + j)) * 64;
                    q0[j] = *(const float4*)(src);
                    q1[j] = *(const float4*)(src + 4);
                }
            }
        }
#pragma unroll
        for (int j = 0; j < 4; j++) {
            if (tbase + j < ntiles) {
                f32x16 acc;
#pragma unroll
                for (int z = 0; z < 16; z++) acc[z] = 0.0f;
#pragma unroll
                for (int s = 0; s < 4; s++) {
                    bf16x8 ah = sh_ah[j * 256 + s * 64 + lane];
                    bf16x8 al = sh_al[j * 256 + s * 64 + lane];
                    acc = __builtin_amdgcn_mfma_f32_32x32x16_bf16(ah, uh[s], acc, 0, 0, 0);
                    acc = __builtin_amdgcn_mfma_f32_32x32x16_bf16(al, uh[s], acc, 0, 0, 0);
                    acc = __builtin_amdgcn_mfma_f32_32x32x16_bf16(ah, ul[s], acc, 0, 0, 0);
                }
                const int tb  = itembase + (tbase + j) * 32;
                const int ib4 = tb + 4 * (lane >> 5);
#pragma unroll
                for (int i = 0; i < 16; i += 2) {
                    const int il0 = (i & 3) + 8 * (i >> 2);
                    const int il1 = ((i + 1) & 3) + 8 * ((i + 1) >> 2);
                    const int item0 = ib4 + il0;
                    const int item1 = ib4 + il1;
                    u32 r0, r1;
                    threefry_pair(rowbase_e + (u32)item0, rowbase_e + (u32)item1, r0, r1);
                    float sA = acc[i], sB = acc[i + 1];
                    sm = fmaxf(sm, fmaxf(sA, sB));
                    if (r0 >= BITS_RAW_T) {               // ~0.25% of items
                        float v = sA + gumbel_from_bits(r0);
                        if (v > t1f) {
                            t2f = t1f; t1f = v;
                            t1p = ((u64)order_map(v) << 32) | (u32)(~(u32)item0);
                        } else t2f = fmaxf(t2f, v);
                    }
                    if (r1 >= BITS_RAW_T) {
                        float v = sB + gumbel_from_bits(r1);
                        if (v > t1f) {
                            t2f = t1f; t1f = v;
                            t1p = ((u64)order_map(v) << 32) | (u32)(~(u32)item1);
                        } else t2f = fmaxf(t2f, v);
                    }
                }
            }
        }
    }

    float bnd = fmaxf(t2f, sm + G_TE);
    {
        u64   op = __shfl_xor(t1p, 32);
        float of = __shfl_xor(t1f, 32);
        float ob = __shfl_xor(bnd, 32);
        if (op > t1p) { bnd = fmaxf(fmaxf(bnd, ob), t1f); t1p = op; t1f = of; }
        else          { bnd = fmaxf(fmaxf(bnd, ob), of); }
    }
    if (lane < 32) {
        wsT1[(size_t)row * S_BLOCKS + sb] = t1p;
        wsB [(size_t)row * S_BLOCKS + sb] = bnd;
    }
}

// ---------------- K3: rowresolve = merge + certify + candidate rescan ------
// Flagged rows (gap <= 2E, ~1/run): rescan ONLY sb-blocks whose
// max(top1_sb, bound_sb) >= F1 - 2E (provably the only candidates).
__global__ __launch_bounds__(256) void rowresolve_kernel(
        const u64* __restrict__ wsT1, const float* __restrict__ wsB,
        const float* __restrict__ wsAM4, const float* __restrict__ unorm,
        const float* __restrict__ uif, const float* __restrict__ A,
        const int* __restrict__ need_replace, float* __restrict__ out) {
    const int row = blockIdx.x, t = threadIdx.x;     // 256 threads
    __shared__ float Us[64];
    __shared__ u64   shP[4];
    __shared__ float shF2[4], shAM[4];
    if (t < 64) Us[t] = uif[row * 64 + t];

    float am = 0.f;
    for (int i = t; i < S_BLOCKS * 4; i += 256) am = fmaxf(am, wsAM4[i]);
    u64 p1 = 0ull; float f1 = -3.0e38f, f2 = -3.0e38f;
    for (int sbk = t; sbk < S_BLOCKS; sbk += 256) {
        u64   ep = wsT1[(size_t)row * S_BLOCKS + sbk];
        float e2 = wsB [(size_t)row * S_BLOCKS + sbk];
        if (ep > p1) { f2 = fmaxf(fmaxf(f1, e2), f2); p1 = ep; f1 = unpack_val(ep); }
        else         { float v = unpack_val(ep); f2 = fmaxf(f2, fmaxf(v, e2)); }
    }
#pragma unroll
    for (int off = 1; off < 64; off <<= 1) {
        u64   op  = __shfl_xor(p1, off);
        float of1 = __shfl_xor(f1, off);
        float of2 = __shfl_xor(f2, off);
        am = fmaxf(am, __shfl_xor(am, off));
        if (op > p1) { f2 = fmaxf(fmaxf(f1, of2), f2); p1 = op; f1 = of1; }
        else         { f2 = fmaxf(f2, fmaxf(of1, of2)); }
    }
    if ((t & 63) == 0) { shP[t >> 6] = p1; shF2[t >> 6] = f2; shAM[t >> 6] = am; }
    __syncthreads();                                  // also publishes Us

    u64 P = shP[0]; float F1 = unpack_val(P), F2 = shF2[0], AM = shAM[0];
#pragma unroll
    for (int w = 1; w < 4; w++) {
        u64 op = shP[w]; float o2 = shF2[w];
        AM = fmaxf(AM, shAM[w]);
        if (op > P) { F2 = fmaxf(fmaxf(F1, o2), F2); P = op; F1 = unpack_val(op); }
        else        { F2 = fmaxf(F2, fmaxf(unpack_val(op), o2)); }
    }
    const float E = 1.5e-4f * unorm[row] * AM + 3.0e-5f;   // R6-verified margin

    if (!(F1 - F2 > 2.0f * E)) {
        const float thresh = F1 - 2.0f * E;
        u64 pk = 0ull;
        for (int sb = 0; sb < S_BLOCKS; sb++) {
            u64   tp = wsT1[(size_t)row * S_BLOCKS + sb];   // broadcast reads
            float bb = wsB [(size_t)row * S_BLOCKS + sb];
            if (fmaxf(unpack_val(tp), bb) >= thresh) {      // candidate sb (~1-2)
                const int item = sb * IPB + t;
                if (item < NITEMS) {
                    u32 rb  = threefry_0_42_xor((u32)row * (u32)NITEMS + (u32)item);
                    float g = gumbel_from_bits(rb);
                    const float4* a4 = (const float4*)(A + (size_t)item * DDIM);
                    float s0 = 0.f, s1 = 0.f;
#pragma unroll
                    for (int k = 0; k < 16; k += 2) {       // R5-verified op order
                        float4 x = a4[k];
                        float4 y = a4[k + 1];
                        s0 = fmaf(x.x, Us[4*k    ], s0);
                        s0 = fmaf(x.y, Us[4*k + 1], s0);
                        s0 = fmaf(x.z, Us[4*k + 2], s0);
                        s0 = fmaf(x.w, Us[4*k + 3], s0);
                        s1 = fmaf(y.x, Us[4*k + 4], s1);
                        s1 = fmaf(y.y, Us[4*k + 5], s1);
                        s1 = fmaf(y.z, Us[4*k + 6], s1);
                        s1 = fmaf(y.w, Us[4*k + 7], s1);
                    }
                    float v = (s0 + s1) + g;
                    u64 c = ((u64)order_map(v) << 32) | (u32)(~(u32)item);
                    if (c > pk) pk = c;
                }
            }
        }
#pragma unroll
        for (int off = 1; off < 64; off <<= 1) {
            u64 o = __shfl_xor(pk, off);
            pk = (o > pk) ? o : pk;
        }
        __syncthreads();                          // reuse shP safely
        if ((t & 63) == 0) shP[t >> 6] = pk;
        __syncthreads();
        P = shP[0];
#pragma unroll
        for (int w = 1; w < 4; w++) if (shP[w] > P) P = shP[w];
    }

    if (t < 64) {
        const int idx = (int)(~(u32)(P & 0xFFFFFFFFull));
        float fr = A[(size_t)idx * DDIM + t];
        out[OUT_FEAT + row * DDIM + t] = fr;
        int   item = need_replace[2 * row + 1];
        float fa   = A[(size_t)item * DDIM + t];
        float dot = fa * fr, na2 = fa * fa, nb2 = fr * fr;
#pragma unroll
        for (int o = 32; o >= 1; o >>= 1) {
            dot += __shfl_down(dot, o);
            na2 += __shfl_down(na2, o);
            nb2 += __shfl_down(nb2, o);
        }
        if (t == 0) {
            out[row] = (float)idx;
            float denom = fmaxf(sqrtf(na2) * sqrtf(nb2), 1e-6f);
            float sim = (dot / denom + 1.0f) * 0.5f;
            float d = sim - 0.5f;
            atomicAdd(&out[OUT_LOSS], d * d * (1.0f / 512.0f));
            atomicAdd(&out[OUT_MSIM], sim * (1.0f / 512.0f));
        }
    }
}

extern "C" void kernel_launch(void* const* d_in, const int* in_sizes, int n_in,
                              void* d_out, int out_size, void* d_ws, size_t ws_size,
                              hipStream_t stream) {
    (void)in_sizes; (void)n_in; (void)out_size; (void)ws_size;
    const int*   need_replace = (const int*)d_in[0];
    const float* UF           = (const float*)d_in[1];
    const float* A            = (const float*)d_in[2];
    const float* W            = (const float*)d_in[3];
    const float* bias         = (const float*)d_in[4];
    float* out = (float*)d_out;

    char* ws = (char*)d_ws;                              // ~2.54 MB total
    u64*   wsT1    = (u64*)  (ws);                       // 512*391*8 = 1601536
    float* wsB     = (float*)(ws + 1601536);             // 800768
    float* uif     = (float*)(ws + 2402304);             // 131072
    float* unorm   = (float*)(ws + 2533376);             // 2048
    float* wsAM4   = (float*)(ws + 2535424);             // 6256

    prep_kernel<<<519, 256, 0, stream>>>(UF, W, bias, A, uif, unorm, wsAM4, out);
    phase1_kernel<<<dim3(S_BLOCKS, 4), 256, 0, stream>>>(A, uif, wsT1, wsB);
    rowresolve_kernel<<<BROWS, 256, 0, stream>>>(wsT1, wsB, wsAM4, unorm, uif, A,
                                                 need_replace, out);
}

// Round 14
// 258.008 us; speedup vs baseline: 4.6318x; 1.0405x over previous
//
#include <hip/hip_runtime.h>
#include <cstdint>

#define NITEMS   100000
#define BROWS    512
#define DDIM     64
#define S_BLOCKS 391        // phase-1 item-blocks (256 items each)
#define IPB      256
#define OUT_FEAT 512
#define OUT_LOSS (512 + 512 * 64)
#define OUT_MSIM (OUT_LOSS + 1)

// Gumbel filter: g monotone in bits; bits >= T <=> g may exceed 6.0.
#define BITS_RAW_T 4284334592u
#define G_TE       6.001f

typedef __attribute__((ext_vector_type(8)))  short  bf16x8;
typedef __attribute__((ext_vector_type(16))) float  f32x16;
typedef unsigned long long u64;
typedef uint32_t u32;

#define ROTL(x, r) __builtin_amdgcn_alignbit((x), (x), 32u - (r))

// ---------------- Threefry-2x32-20, key=(0,42). VERIFIED R4 (absmax 0.0):
// partitionable scheme, counters (hi=0, lo=e), output = bits1 ^ bits2.
__device__ __forceinline__ u32 threefry_0_42_xor(u32 e) {
    const u32 K1 = 42u;
    const u32 K2 = 0x1BD11BDAu ^ 42u;   // K0 = 0
    u32 x0 = 0u;
    u32 x1 = e + K1;
#define TFR(r) { x0 += x1; x1 = ROTL(x1, r) ^ x0; }
    TFR(13u) TFR(15u) TFR(26u) TFR(6u)
    x0 += K1;  x1 += K2 + 1u;
    TFR(17u) TFR(29u) TFR(16u) TFR(24u)
    x0 += K2;  x1 += 2u;
    TFR(13u) TFR(15u) TFR(26u) TFR(6u)
    x1 += K1 + 3u;
    TFR(17u) TFR(29u) TFR(16u) TFR(24u)
    x0 += K1;  x1 += K2 + 4u;
    TFR(13u) TFR(15u) TFR(26u) TFR(6u)
    x0 += K2;  x1 += 5u;
#undef TFR
    return x0 ^ x1;
}

// Pair version: 2 independent chains interleaved (ILP 2 on the dep chain).
__device__ __forceinline__ void threefry_pair(u32 ea, u32 eb, u32& oa, u32& ob) {
    const u32 K1 = 42u;
    const u32 K2 = 0x1BD11BDAu ^ 42u;
    u32 a0 = 0u, a1 = ea + K1;
    u32 b0 = 0u, b1 = eb + K1;
#define TFR2(r) { a0 += a1; b0 += b1; a1 = ROTL(a1, r) ^ a0; b1 = ROTL(b1, r) ^ b0; }
    TFR2(13u) TFR2(15u) TFR2(26u) TFR2(6u)
    a0 += K1; a1 += K2 + 1u;  b0 += K1; b1 += K2 + 1u;
    TFR2(17u) TFR2(29u) TFR2(16u) TFR2(24u)
    a0 += K2; a1 += 2u;       b0 += K2; b1 += 2u;
    TFR2(13u) TFR2(15u) TFR2(26u) TFR2(6u)
    a1 += K1 + 3u;            b1 += K1 + 3u;
    TFR2(17u) TFR2(29u) TFR2(16u) TFR2(24u)
    a0 += K1; a1 += K2 + 4u;  b0 += K1; b1 += K2 + 4u;
    TFR2(13u) TFR2(15u) TFR2(26u) TFR2(6u)
    a0 += K2; a1 += 5u;       b0 += K2; b1 += 5u;
#undef TFR2
    oa = a0 ^ a1; ob = b0 ^ b1;
}

__device__ __forceinline__ float gumbel_from_bits(u32 b) {   // precise logf REQUIRED
    float f = __uint_as_float((b >> 9) | 0x3F800000u) - 1.0f;
    f = fmaxf(f, 1.17549435e-38f);
    return -logf(-logf(f));
}
__device__ __forceinline__ u32 order_map(float v) {
    u32 x = __float_as_uint(v);
    return (x & 0x80000000u) ? ~x : (x | 0x80000000u);
}
__device__ __forceinline__ float unpack_val(u64 p) {
    u32 x = (u32)(p >> 32);
    u32 f = (x & 0x80000000u) ? (x & 0x7FFFFFFFu) : ~x;
    return __uint_as_float(f);
}
__device__ __forceinline__ short f32_to_bf16_rne(float f) {
    u32 b = __float_as_uint(f);
    u32 r = (b + 0x7FFFu + ((b >> 16) & 1u)) >> 16;
    return (short)r;
}
__device__ __forceinline__ float bf16_to_f32(short h) {
    return __uint_as_float(((u32)(uint16_t)h) << 16);
}

// ---------------- K1: prep = uif GEMM (W^T in LDS) + norms (no atomics) ----
__global__ void prep_kernel(const float* __restrict__ UF, const float* __restrict__ W,
                            const float* __restrict__ bias, const float* __restrict__ A,
                            float* __restrict__ uif, float* __restrict__ unorm,
                            float* __restrict__ wsAM4, float* __restrict__ out) {
    const int t = threadIdx.x, b = blockIdx.x;
    if (b == 0 && t == 0) { out[OUT_LOSS] = 0.f; out[OUT_MSIM] = 0.f; }
    if (b < 128) {
        __shared__ float Wt[128 * 65];
        for (int i = t; i < 8192; i += 256) {
            int d = i >> 7, k = i & 127;
            Wt[k * 65 + d] = W[i];
        }
        __syncthreads();
        const int row = b * 4 + (t >> 6);
        const int d   = t & 63;
        const float* u = UF + row * 128;
        float s = 0.f;
#pragma unroll 4
        for (int k = 0; k < 128; k++) s = fmaf(u[k], Wt[k * 65 + d], s);
        s += bias[d];
        uif[row * 64 + d] = s;
        float q = s * s;
#pragma unroll
        for (int o = 32; o >= 1; o >>= 1) q += __shfl_xor(q, o);
        if (d == 0) unorm[row] = sqrtf(q);
    } else {
        const int item = (b - 128) * 256 + t;
        float q = 0.f;
        if (item < NITEMS) {
            const float4* r = (const float4*)(A + (size_t)item * DDIM);
#pragma unroll
            for (int k = 0; k < 16; k++) {
                float4 x = r[k];
                q = fmaf(x.x, x.x, q); q = fmaf(x.y, x.y, q);
                q = fmaf(x.z, x.z, q); q = fmaf(x.w, x.w, q);
            }
        }
        float n = sqrtf(q);
#pragma unroll
        for (int o = 32; o >= 1; o >>= 1) n = fmaxf(n, __shfl_xor(n, o));
        if ((t & 63) == 0) wsAM4[(b - 128) * 4 + (t >> 6)] = n;
    }
}

// ---------------- K2: phase-1 MFMA score + filtered gumbel + top-2 ---------
// (256,4): 128-VGPR budget fits the kernel's natural ~60-76 VGPR working set
// (R13's (256,5) forced 48 VGPRs -> scratch spills, WRITE_SIZE 12.7->40.8MB).
// Occupancy ceiling 50%; LDS 4 x 32KB = 128KB <= 160KB.
__global__ __launch_bounds__(256, 4) void phase1_kernel(
        const float* __restrict__ A, const float* __restrict__ uif,
        u64* __restrict__ wsT1, float* __restrict__ wsB) {
    __shared__ bf16x8 sh_ah[4 * 256];    // 16 KB
    __shared__ bf16x8 sh_al[4 * 256];    // 16 KB
    const int tid  = threadIdx.x;
    const int lane = tid & 63;
    const int wv   = tid >> 6;
    const int rg   = blockIdx.y;
    const int sb   = blockIdx.x;
    const int itembase = sb * IPB;
    const int ntiles = min(8, (NITEMS - itembase + 31) >> 5);   // 8 or 5; tiles always full
    const int row   = rg * 128 + wv * 32 + (lane & 31);
    const int khalf = (lane >> 5) * 8;

    bf16x8 uh[4], ul[4];
#pragma unroll
    for (int s = 0; s < 4; s++) {
        const float* src = uif + row * 64 + khalf + 16 * s;
        float4 v0 = *(const float4*)src;
        float4 v1 = *(const float4*)(src + 4);
        float vv[8] = {v0.x, v0.y, v0.z, v0.w, v1.x, v1.y, v1.z, v1.w};
        bf16x8 h, l2;
#pragma unroll
        for (int j = 0; j < 8; j++) {
            short hh = f32_to_bf16_rne(vv[j]);
            float r  = vv[j] - bf16_to_f32(hh);
            h[j] = hh; l2[j] = f32_to_bf16_rne(r);
        }
        uh[s] = h; ul[s] = l2;
    }

    u64 t1p = 0ull; float t1f = -3.0e38f, t2f = -3.0e38f, sm = -3.0e38f;
    const u32 rowbase_e = (u32)row * (u32)NITEMS;

    const int s_i   = tid & 31;
    const int s_c   = tid >> 5;
    const int s_dst = (s_c >> 1) * 64 + s_i + 32 * (s_c & 1);   // R7-verified map
    const float* s_srcbase = A + (size_t)s_i * 64 + 8 * s_c;

    float4 q0[4], q1[4];
#pragma unroll
    for (int j = 0; j < 4; j++) {
        const float* src = s_srcbase + (size_t)(itembase + 32 * j) * 64;
        q0[j] = *(const float4*)(src);
        q1[j] = *(const float4*)(src + 4);
    }

    for (int g = 0; g < 2; g++) {
        const int tbase = g * 4;
        __syncthreads();
#pragma unroll
        for (int j = 0; j < 4; j++) {
            if (tbase + j < ntiles) {
                float vv[8] = {q0[j].x, q0[j].y, q0[j].z, q0[j].w,
                               q1[j].x, q1[j].y, q1[j].z, q1[j].w};
                bf16x8 h, l2;
#pragma unroll
                for (int k = 0; k < 8; k++) {
                    short hh = f32_to_bf16_rne(vv[k]);
                    float r  = vv[k] - bf16_to_f32(hh);
                    h[k] = hh; l2[k] = f32_to_bf16_rne(r);
                }
                sh_ah[j * 256 + s_dst] = h; sh_al[j * 256 + s_dst] = l2;
            }
        }
        __syncthreads();
        if (g == 0) {
#pragma unroll
            for (int j = 0; j < 4; j++) {
                if (4 + j < ntiles) {
                    const float* src = s_srcbase + (size_t)(itembase + 32 * (4 + j)) * 64;
                    q0[j] = *(const float4*)(src);
                    q1[j] = *(const float4*)(src + 4);
                }
            }
        }
#pragma unroll
        for (int j = 0; j < 4; j++) {
            if (tbase + j < ntiles) {
                f32x16 acc;
#pragma unroll
                for (int z = 0; z < 16; z++) acc[z] = 0.0f;
#pragma unroll
                for (int s = 0; s < 4; s++) {
                    bf16x8 ah = sh_ah[j * 256 + s * 64 + lane];
                    bf16x8 al = sh_al[j * 256 + s * 64 + lane];
                    acc = __builtin_amdgcn_mfma_f32_32x32x16_bf16(ah, uh[s], acc, 0, 0, 0);
                    acc = __builtin_amdgcn_mfma_f32_32x32x16_bf16(al, uh[s], acc, 0, 0, 0);
                    acc = __builtin_amdgcn_mfma_f32_32x32x16_bf16(ah, ul[s], acc, 0, 0, 0);
                }
                const int tb  = itembase + (tbase + j) * 32;
                const int ib4 = tb + 4 * (lane >> 5);
#pragma unroll
                for (int i = 0; i < 16; i += 2) {
                    const int il0 = (i & 3) + 8 * (i >> 2);
                    const int il1 = ((i + 1) & 3) + 8 * ((i + 1) >> 2);
                    const int item0 = ib4 + il0;
                    const int item1 = ib4 + il1;
                    u32 r0, r1;
                    threefry_pair(rowbase_e + (u32)item0, rowbase_e + (u32)item1, r0, r1);
                    float sA = acc[i], sB = acc[i + 1];
                    sm = fmaxf(sm, fmaxf(sA, sB));
                    if (r0 >= BITS_RAW_T) {               // ~0.25% of items
                        float v = sA + gumbel_from_bits(r0);
                        if (v > t1f) {
                            t2f = t1f; t1f = v;
                            t1p = ((u64)order_map(v) << 32) | (u32)(~(u32)item0);
                        } else t2f = fmaxf(t2f, v);
                    }
                    if (r1 >= BITS_RAW_T) {
                        float v = sB + gumbel_from_bits(r1);
                        if (v > t1f) {
                            t2f = t1f; t1f = v;
                            t1p = ((u64)order_map(v) << 32) | (u32)(~(u32)item1);
                        } else t2f = fmaxf(t2f, v);
                    }
                }
            }
        }
    }

    float bnd = fmaxf(t2f, sm + G_TE);
    {
        u64   op = __shfl_xor(t1p, 32);
        float of = __shfl_xor(t1f, 32);
        float ob = __shfl_xor(bnd, 32);
        if (op > t1p) { bnd = fmaxf(fmaxf(bnd, ob), t1f); t1p = op; t1f = of; }
        else          { bnd = fmaxf(fmaxf(bnd, ob), of); }
    }
    if (lane < 32) {
        wsT1[(size_t)row * S_BLOCKS + sb] = t1p;
        wsB [(size_t)row * S_BLOCKS + sb] = bnd;
    }
}

// ---------------- K3: rowresolve = merge + certify + candidate rescan ------
// Flagged rows (gap <= 2E, ~1/run): rescan ONLY sb-blocks whose
// max(top1_sb, bound_sb) >= F1 - 2E (provably the only candidates).
__global__ __launch_bounds__(256) void rowresolve_kernel(
        const u64* __restrict__ wsT1, const float* __restrict__ wsB,
        const float* __restrict__ wsAM4, const float* __restrict__ unorm,
        const float* __restrict__ uif, const float* __restrict__ A,
        const int* __restrict__ need_replace, float* __restrict__ out) {
    const int row = blockIdx.x, t = threadIdx.x;     // 256 threads
    __shared__ float Us[64];
    __shared__ u64   shP[4];
    __shared__ float shF2[4], shAM[4];
    if (t < 64) Us[t] = uif[row * 64 + t];

    float am = 0.f;
    for (int i = t; i < S_BLOCKS * 4; i += 256) am = fmaxf(am, wsAM4[i]);
    u64 p1 = 0ull; float f1 = -3.0e38f, f2 = -3.0e38f;
    for (int sbk = t; sbk < S_BLOCKS; sbk += 256) {
        u64   ep = wsT1[(size_t)row * S_BLOCKS + sbk];
        float e2 = wsB [(size_t)row * S_BLOCKS + sbk];
        if (ep > p1) { f2 = fmaxf(fmaxf(f1, e2), f2); p1 = ep; f1 = unpack_val(ep); }
        else         { float v = unpack_val(ep); f2 = fmaxf(f2, fmaxf(v, e2)); }
    }
#pragma unroll
    for (int off = 1; off < 64; off <<= 1) {
        u64   op  = __shfl_xor(p1, off);
        float of1 = __shfl_xor(f1, off);
        float of2 = __shfl_xor(f2, off);
        am = fmaxf(am, __shfl_xor(am, off));
        if (op > p1) { f2 = fmaxf(fmaxf(f1, of2), f2); p1 = op; f1 = of1; }
        else         { f2 = fmaxf(f2, fmaxf(of1, of2)); }
    }
    if ((t & 63) == 0) { shP[t >> 6] = p1; shF2[t >> 6] = f2; shAM[t >> 6] = am; }
    __syncthreads();                                  // also publishes Us

    u64 P = shP[0]; float F1 = unpack_val(P), F2 = shF2[0], AM = shAM[0];
#pragma unroll
    for (int w = 1; w < 4; w++) {
        u64 op = shP[w]; float o2 = shF2[w];
        AM = fmaxf(AM, shAM[w]);
        if (op > P) { F2 = fmaxf(fmaxf(F1, o2), F2); P = op; F1 = unpack_val(op); }
        else        { F2 = fmaxf(F2, fmaxf(unpack_val(op), o2)); }
    }
    const float E = 1.5e-4f * unorm[row] * AM + 3.0e-5f;   // R6-verified margin

    if (!(F1 - F2 > 2.0f * E)) {
        const float thresh = F1 - 2.0f * E;
        u64 pk = 0ull;
        for (int sb = 0; sb < S_BLOCKS; sb++) {
            u64   tp = wsT1[(size_t)row * S_BLOCKS + sb];   // broadcast reads
            float bb = wsB [(size_t)row * S_BLOCKS + sb];
            if (fmaxf(unpack_val(tp), bb) >= thresh) {      // candidate sb (~1-2)
                const int item = sb * IPB + t;
                if (item < NITEMS) {
                    u32 rb  = threefry_0_42_xor((u32)row * (u32)NITEMS + (u32)item);
                    float g = gumbel_from_bits(rb);
                    const float4* a4 = (const float4*)(A + (size_t)item * DDIM);
                    float s0 = 0.f, s1 = 0.f;
#pragma unroll
                    for (int k = 0; k < 16; k += 2) {       // R5-verified op order
                        float4 x = a4[k];
                        float4 y = a4[k + 1];
                        s0 = fmaf(x.x, Us[4*k    ], s0);
                        s0 = fmaf(x.y, Us[4*k + 1], s0);
                        s0 = fmaf(x.z, Us[4*k + 2], s0);
                        s0 = fmaf(x.w, Us[4*k + 3], s0);
                        s1 = fmaf(y.x, Us[4*k + 4], s1);
                        s1 = fmaf(y.y, Us[4*k + 5], s1);
                        s1 = fmaf(y.z, Us[4*k + 6], s1);
                        s1 = fmaf(y.w, Us[4*k + 7], s1);
                    }
                    float v = (s0 + s1) + g;
                    u64 c = ((u64)order_map(v) << 32) | (u32)(~(u32)item);
                    if (c > pk) pk = c;
                }
            }
        }
#pragma unroll
        for (int off = 1; off < 64; off <<= 1) {
            u64 o = __shfl_xor(pk, off);
            pk = (o > pk) ? o : pk;
        }
        __syncthreads();                          // reuse shP safely
        if ((t & 63) == 0) shP[t >> 6] = pk;
        __syncthreads();
        P = shP[0];
#pragma unroll
        for (int w = 1; w < 4; w++) if (shP[w] > P) P = shP[w];
    }

    if (t < 64) {
        const int idx = (int)(~(u32)(P & 0xFFFFFFFFull));
        float fr = A[(size_t)idx * DDIM + t];
        out[OUT_FEAT + row * DDIM + t] = fr;
        int   item = need_replace[2 * row + 1];
        float fa   = A[(size_t)item * DDIM + t];
        float dot = fa * fr, na2 = fa * fa, nb2 = fr * fr;
#pragma unroll
        for (int o = 32; o >= 1; o >>= 1) {
            dot += __shfl_down(dot, o);
            na2 += __shfl_down(na2, o);
            nb2 += __shfl_down(nb2, o);
        }
        if (t == 0) {
            out[row] = (float)idx;
            float denom = fmaxf(sqrtf(na2) * sqrtf(nb2), 1e-6f);
            float sim = (dot / denom + 1.0f) * 0.5f;
            float d = sim - 0.5f;
            atomicAdd(&out[OUT_LOSS], d * d * (1.0f / 512.0f));
            atomicAdd(&out[OUT_MSIM], sim * (1.0f / 512.0f));
        }
    }
}

extern "C" void kernel_launch(void* const* d_in, const int* in_sizes, int n_in,
                              void* d_out, int out_size, void* d_ws, size_t ws_size,
                              hipStream_t stream) {
    (void)in_sizes; (void)n_in; (void)out_size; (void)ws_size;
    const int*   need_replace = (const int*)d_in[0];
    const float* UF           = (const float*)d_in[1];
    const float* A            = (const float*)d_in[2];
    const float* W            = (const float*)d_in[3];
    const float* bias         = (const float*)d_in[4];
    float* out = (float*)d_out;

    char* ws = (char*)d_ws;                              // ~2.54 MB total
    u64*   wsT1    = (u64*)  (ws);                       // 512*391*8 = 1601536
    float* wsB     = (float*)(ws + 1601536);             // 800768
    float* uif     = (float*)(ws + 2402304);             // 131072
    float* unorm   = (float*)(ws + 2533376);             // 2048
    float* wsAM4   = (float*)(ws + 2535424);             // 6256

    prep_kernel<<<519, 256, 0, stream>>>(UF, W, bias, A, uif, unorm, wsAM4, out);
    phase1_kernel<<<dim3(S_BLOCKS, 4), 256, 0, stream>>>(A, uif, wsT1, wsB);
    rowresolve_kernel<<<BROWS, 256, 0, stream>>>(wsT1, wsB, wsAM4, unorm, uif, A,
                                                 need_replace, out);
}